// Round 14
// baseline (120.056 us; speedup 1.0000x reference)
//
#include <hip/hip_runtime.h>

// TangentSpaceLoss: loss = (1/B^2) sum_ij softmax_j(E E^T)_ij * ||v_i - v_j||^2
// B=8192, G=512, D=64.
//
// R27: R26 post-mortem — pad worked (conflicts 532K->0) but accT[4]+stored
// p[4][4] re-tipped the allocator (WRITE 4.06->19.1MB spill); net ~0.
// Dispatch-ID spacing (28/iter) shows ~25 harness restore dispatches/iter
// = the ~64us fixed cost (uncontrollable). R27 keeps pad+batch, sheds reg
// cost: predicates computed for the single per-im ballot but NOT stored —
// recomputed (2 ops) inside the rare branch body. Saves 16 live bools,
// shortens accT live range. Else R26-exact.
// Sentinel: WRITE 4.06MB. Predict k_mega ~51-53, total ~116-118.
// If spill persists -> revert R25+pad, declare convergence.
//   G: LDS-staged fp8 MFMA K=512 (m97): lane-linear VF8, 16x
//      global_load_lds(16B)/chunk, dbuf, 1 barrier/chunk, linear ds_read_b128.
//   S: fp16 MFMA (EFh frag-linear, B-frags hoisted), ballot-skip epilogue,
//      reg-hoisted predicates, per-im batched ballot (recompute-in-body),
//      2-stage partial reduce, padded scr planes.
// Selection: s > min(ne_i,ne_j)-32 (safe superset). Softmax shift ne_i;
// diagonal w=1, wd=0 -> Z preinit 1.
//
// VF8: [rt 512][c 8][lane 64][16B]; lane l = q*16+m holds A-row m,
// K-quad q (bytes 0-7 = kc0, 8-15 = kc1).
// EFh: [rt 512][kc 2][m 16][k' 32] halfs.

#define SEL_T 32.0f

typedef _Float16 half8 __attribute__((ext_vector_type(8)));
typedef float    f32x4 __attribute__((ext_vector_type(4)));
typedef long     l2t   __attribute__((ext_vector_type(2)));

#define MFMA16(a, b, c) __builtin_amdgcn_mfma_f32_16x16x32_f16(a, b, c, 0, 0, 0)
#define MFMA8(a, b, c)  __builtin_amdgcn_mfma_f32_16x16x32_fp8_fp8(a, b, c, 0, 0, 0)

// Shared super-tile decode: blk0 -> (bx<=by), XCD-windowed.
__device__ __forceinline__ void st_decode(int blk0, int& bx, int& by) {
    int g = (blk0 & 7) * 260 + (blk0 >> 3);
    int SY = 0;
#pragma unroll
    for (int s = 1; s < 8; ++s) if (32 * s * s + 4 * s <= g) SY = s;
    int rr = g - (32 * SY * SY + 4 * SY);
    if (rr < 64 * SY) {                         // off-diagonal ST (full 8x8)
        int SX = rr >> 6, t = rr & 63;
        bx = (SX << 3) + (t & 7);
        by = (SY << 3) + (t >> 3);
    } else {                                    // diagonal ST (36 blocks)
        int t = rr - 64 * SY;
        int ly = 0;
#pragma unroll
        for (int s = 1; s < 8; ++s) if (s * (s + 1) / 2 <= t) ly = s;
        int lx = t - ly * (ly + 1) / 2;
        bx = (SY << 3) + lx;
        by = (SY << 3) + ly;
    }
}

// ---------------- K1: norms + fp8 V + fp16 E layouts + Z/num init -------
__global__ __launch_bounds__(256) void k_prep(
    const float* __restrict__ V, const float* __restrict__ E,
    float* __restrict__ n, float* __restrict__ ne,
    float* __restrict__ Z, float* __restrict__ num,
    unsigned char* __restrict__ VF8, _Float16* __restrict__ EFh,
    unsigned* __restrict__ cnt) {
    int rt = blockIdx.x;                       // 512 row-tiles of 16 rows
    int tid = threadIdx.x, wave = tid >> 6, lane = tid & 63;
    if (rt == 0 && tid == 0) *cnt = 0;
    int m = lane >> 2, q = lane & 3;
    int row = rt * 16 + m;
    const float* vr = V + (size_t)row * 512;
    float sn = 0.f;
#pragma unroll
    for (int it = 0; it < 2; ++it) {
        int c = wave + it * 4;                 // K-chunk of 64
        const float4* p0 = (const float4*)(vr + c * 64 + q * 8);
        const float4* p1 = (const float4*)(vr + c * 64 + 32 + q * 8);
        float4 a0 = p0[0], a1 = p0[1], b0 = p1[0], b1 = p1[1];
        int w0 = 0, w1 = 0, w2 = 0, w3 = 0;
        w0 = __builtin_amdgcn_cvt_pk_fp8_f32(a0.x, a0.y, w0, false);
        w0 = __builtin_amdgcn_cvt_pk_fp8_f32(a0.z, a0.w, w0, true);
        w1 = __builtin_amdgcn_cvt_pk_fp8_f32(a1.x, a1.y, w1, false);
        w1 = __builtin_amdgcn_cvt_pk_fp8_f32(a1.z, a1.w, w1, true);
        w2 = __builtin_amdgcn_cvt_pk_fp8_f32(b0.x, b0.y, w2, false);
        w2 = __builtin_amdgcn_cvt_pk_fp8_f32(b0.z, b0.w, w2, true);
        w3 = __builtin_amdgcn_cvt_pk_fp8_f32(b1.x, b1.y, w3, false);
        w3 = __builtin_amdgcn_cvt_pk_fp8_f32(b1.z, b1.w, w3, true);
        uint4 o;
        o.x = (unsigned)w0; o.y = (unsigned)w1;
        o.z = (unsigned)w2; o.w = (unsigned)w3;
        // LANE-LINEAR layout: frag for (m,q) -> reader-lane l = q*16+m,
        // byte offset l*16 = (q<<8) + (m<<4).
        *(uint4*)(VF8 + (((size_t)rt * 8 + c) << 10) + ((size_t)q << 8) + ((size_t)m << 4)) = o;
        sn += a0.x*a0.x + a0.y*a0.y + a0.z*a0.z + a0.w*a0.w
            + a1.x*a1.x + a1.y*a1.y + a1.z*a1.z + a1.w*a1.w
            + b0.x*b0.x + b0.y*b0.y + b0.z*b0.z + b0.w*b0.w
            + b1.x*b1.x + b1.y*b1.y + b1.z*b1.z + b1.w*b1.w;
    }
    __shared__ float sred[4][64];
    sred[wave][lane] = sn;
    __syncthreads();
    if (tid < 16) {
        float s = 0.f;
#pragma unroll
        for (int w = 0; w < 4; ++w)
#pragma unroll
            for (int qq = 0; qq < 4; ++qq) s += sred[w][tid * 4 + qq];
        int rr = rt * 16 + tid;
        n[rr] = s;
        Z[rr] = 1.0f;                          // diagonal w=1, wd=0
        num[rr] = 0.0f;
    }
    // E: threads 0..127: rl = t>>3, u = t&7, k in [u*8, u*8+8)
    if (tid < 128) {
        int rl = tid >> 3, u = tid & 7;
        int erow = rt * 16 + rl;
        const float4* er = (const float4*)(E + (size_t)erow * 64);
        float4 x0 = er[u * 2], x1 = er[u * 2 + 1];
        float xf[8] = {x0.x, x0.y, x0.z, x0.w, x1.x, x1.y, x1.z, x1.w};
        half8 h;
        float se = 0.f;
#pragma unroll
        for (int k = 0; k < 8; ++k) {
            h[k] = (_Float16)xf[k];
            se += xf[k] * xf[k];
        }
        int kc = u >> 2, qq = u & 3;
        *(half8*)(EFh + ((size_t)rt * 2 + kc) * 512 + rl * 32 + qq * 8) = h;
        se += __shfl_xor(se, 1, 64);
        se += __shfl_xor(se, 2, 64);
        se += __shfl_xor(se, 4, 64);
        if (u == 0) ne[erow] = se;
    }
}

// ---------------- K2: LDS-staged tile kernel (m97 structure) ------------
// 256 thr = 4 waves in 2x2 grid; wave tile 64x64 = 4x4 MFMA tiles.
// Per K-chunk: 16 async global_load_lds (4/wave) stage 16KB; dbuf; 1 barrier.
__global__ __launch_bounds__(256, 3) void k_mega(
    const unsigned char* __restrict__ VF8, const _Float16* __restrict__ EFh,
    const float* __restrict__ ne, const float* __restrict__ nrm,
    float* __restrict__ Z, float* __restrict__ num) {
    int bx, by;
    st_decode(blockIdx.x, bx, by);
    int i0 = bx << 7, j0 = by << 7;
    bool diag = (bx == by);

    __shared__ unsigned char ldsV[2][16384];   // [buf][slot 16][1KB]; 0-7 A, 8-15 B
    __shared__ float sNeI[128], sNeJ[128], sNI[128], sNJ[128];
    // scr: zi 8 planes x 132 (pad: worst 2-way = free), ni 8 x 132,
    //      zj 4 x 128, nj 4 x 128
    __shared__ float scr[2112 + 1024];

    int tid = threadIdx.x;
    if (tid < 128) { sNeI[tid] = ne[i0 + tid]; sNI[tid] = nrm[i0 + tid]; }
    else { sNeJ[tid - 128] = ne[j0 + tid - 128]; sNJ[tid - 128] = nrm[j0 + tid - 128]; }

    int wave = tid >> 6, lane = tid & 63;
    int m = lane & 15, quad = lane >> 4;
    int wi = wave & 1, wj = wave >> 1;
    int rtA0 = i0 >> 4, rtB0 = j0 >> 4;
    size_t loH = (size_t)(m * 32 + quad * 8);   // halfs (E frags)
    size_t lo16 = (size_t)lane << 4;            // lane-linear 16B frag offset

    __syncthreads();   // norms staged (also pre-loop barrier)

    // stage slot s (0-7: A rt rtA0+s; 8-15: B rt rtB0+s-8), chunk c -> buf
#define STAGE(buf, c)                                                           \
    {                                                                           \
        _Pragma("unroll")                                                       \
        for (int k = 0; k < 4; ++k) {                                           \
            int s = (wave << 2) + k;                                            \
            int rt = (s < 8) ? (rtA0 + s) : (rtB0 + s - 8);                     \
            __builtin_amdgcn_global_load_lds(                                   \
                (const unsigned int*)(VF8 + (((size_t)rt * 8 + (c)) << 10) + lo16), \
                (unsigned int*)(&ldsV[buf][(size_t)s << 10]), 16, 0, 0);        \
        }                                                                       \
    }

    // ---- G phase: K=512, 8 chunks; async-staged LDS, dbuf, 1 barrier/chunk
    f32x4 gacc[4][4] = {};
    STAGE(0, 0);
#pragma unroll
    for (int c = 0; c < 8; ++c) {
        __syncthreads();                       // buf[c&1] staged (vmcnt0+bar)
        if (c < 7) STAGE((c + 1) & 1, c + 1);  // async into other buf (race-free)
        l2t a[4], b[4];
#pragma unroll
        for (int im = 0; im < 4; ++im)
            a[im] = *(const l2t*)(&ldsV[c & 1][(size_t)((wi << 2) + im) << 10] + lo16);
#pragma unroll
        for (int jn = 0; jn < 4; ++jn)
            b[jn] = *(const l2t*)(&ldsV[c & 1][(size_t)(8 + (wj << 2) + jn) << 10] + lo16);
#pragma unroll
        for (int jn = 0; jn < 4; ++jn)
#pragma unroll
            for (int im = 0; im < 4; ++im) {
                gacc[im][jn] = MFMA8(a[im][0], b[jn][0], gacc[im][jn]);
                gacc[im][jn] = MFMA8(a[im][1], b[jn][1], gacc[im][jn]);
            }
    }
#undef STAGE

    // ---- fused S phase + epilogue (batched ballot, recompute-in-body) ----
    int rtA = rtA0 + wi * 4;
    int rtB = rtB0 + wj * 4;
    half8 bh[4][2];
#pragma unroll
    for (int jn = 0; jn < 4; ++jn) {
        size_t bb = (size_t)(rtB + jn) * 2 * 512 + loH;
        bh[jn][0] = *(const half8*)(EFh + bb);
        bh[jn][1] = *(const half8*)(EFh + bb + 512);
    }
    // hoisted predicate inputs: bj[jn] = ne_j - SEL_T (4 regs)
    float bj[4];
#pragma unroll
    for (int jn = 0; jn < 4; ++jn) bj[jn] = sNeJ[(wj << 6) + jn * 16 + m] - SEL_T;

    float zj[4] = {}, nj_[4] = {};
#pragma unroll
    for (int im = 0; im < 4; ++im) {
        size_t ab = (size_t)(rtA + im) * 2 * 512 + loH;
        half8 ah0 = *(const half8*)(EFh + ab);
        half8 ah1 = *(const half8*)(EFh + ab + 512);
        // one vector read: nei for rows quad*4..quad*4+3, pre-shifted
        int ibase = (wi << 6) + im * 16 + quad * 4;
        f32x4 ai4 = *(const f32x4*)(sNeI + ibase);
        ai4[0] -= SEL_T; ai4[1] -= SEL_T; ai4[2] -= SEL_T; ai4[3] -= SEL_T;
        f32x4 zi4 = {0.f, 0.f, 0.f, 0.f};
        f32x4 ni4 = {0.f, 0.f, 0.f, 0.f};
        // batch: all 4 jn ACC tiles back-to-back (8 pipelined MFMA16s)
        f32x4 accT[4];
#pragma unroll
        for (int jn = 0; jn < 4; ++jn) {
            f32x4 t = {0.f, 0.f, 0.f, 0.f};
            t = MFMA16(ah0, bh[jn][0], t);
            accT[jn] = MFMA16(ah1, bh[jn][1], t);
        }
        // 16 predicates -> ONE ballot; predicates NOT stored (recomputed
        // in the rare branch body: 2 ops each — saves 16 live bools)
        bool anyp = false;
#pragma unroll
        for (int jn = 0; jn < 4; ++jn) {
            int jl = (wj << 6) + jn * 16 + m;
#pragma unroll
            for (int r = 0; r < 4; ++r) {
                bool pp = accT[jn][r] > fminf(ai4[r], bj[jn]);
                if (diag) pp = pp && ((i0 + ibase + r) < (j0 + jl));
                anyp |= pp;
            }
        }
        if (__builtin_amdgcn_ballot_w64(anyp)) {       // wave-uniform skip
#pragma unroll
            for (int jn = 0; jn < 4; ++jn) {
                int jl = (wj << 6) + jn * 16 + m;
                float nej = sNeJ[jl], nnj = sNJ[jl];
                f32x4 g4 = gacc[im][jn];
#pragma unroll
                for (int r = 0; r < 4; ++r) {
                    bool pp = accT[jn][r] > fminf(ai4[r], bj[jn]);
                    if (diag) pp = pp && ((i0 + ibase + r) < (j0 + jl));
                    if (pp) {
                        int il = ibase + r;
                        float nei = sNeI[il], nni = sNI[il];
                        float s = accT[jn][r];
                        float wiw = __expf(s - nei);
                        float wjw = __expf(s - nej);
                        float wd = nni + nnj - 2.f * g4[r];
                        zi4[r] += wiw;  ni4[r] += wiw * wd;
                        zj[jn] += wjw;  nj_[jn] += wjw * wd;
                    }
                }
            }
        }
        // i-side: 2-stage reduce (groups of 4 m-lanes), write 4 partials/row
#pragma unroll
        for (int msk = 1; msk < 4; msk <<= 1) {
#pragma unroll
            for (int r = 0; r < 4; ++r) {
                zi4[r] += __shfl_xor(zi4[r], msk, 64);
                ni4[r] += __shfl_xor(ni4[r], msk, 64);
            }
        }
        if ((m & 3) == 0) {
            int k = m >> 2;
            *(f32x4*)(scr + ((wj << 2) + k) * 132 + ibase)        = zi4;
            *(f32x4*)(scr + 1056 + ((wj << 2) + k) * 132 + ibase) = ni4;
        }
        __builtin_amdgcn_sched_barrier(0);     // fence cross-im hoisting
    }
    // j-side: 1-stage reduce (quad pairs), write 2 partials/col
#pragma unroll
    for (int jn = 0; jn < 4; ++jn) {
        zj[jn]  += __shfl_xor(zj[jn],  16, 64);
        nj_[jn] += __shfl_xor(nj_[jn], 16, 64);
    }
    if ((quad & 1) == 0) {
        int h = quad >> 1;
#pragma unroll
        for (int jn = 0; jn < 4; ++jn) {
            int jl = (wj << 6) + jn * 16 + m;
            scr[2112 + ((wi << 1) + h) * 128 + jl] = zj[jn];
            scr[2624 + ((wi << 1) + h) * 128 + jl] = nj_[jn];
        }
    }
    __syncthreads();
    // fold partial planes -> direct device atomics (zero-skip for empty rows)
    if (tid < 128) {
        float az = 0.f, an = 0.f;
#pragma unroll
        for (int p = 0; p < 8; ++p) {
            az += scr[p * 132 + tid];
            an += scr[1056 + p * 132 + tid];
        }
        if (az != 0.f || an != 0.f) {
            atomicAdd(Z + i0 + tid,   az);
            atomicAdd(num + i0 + tid, an);
        }
    } else {
        int cidx = tid - 128;
        float az = scr[2112 + cidx] + scr[2240 + cidx] + scr[2368 + cidx] + scr[2496 + cidx];
        float an = scr[2624 + cidx] + scr[2752 + cidx] + scr[2880 + cidx] + scr[3008 + cidx];
        if (az != 0.f || an != 0.f) {
            atomicAdd(Z + j0 + cidx,   az);
            atomicAdd(num + j0 + cidx, an);
        }
    }
}

// ------- K3: trivial 8192-row reduce + last-block final fold ------------
__global__ __launch_bounds__(256) void k_red(
    const float* __restrict__ Z, const float* __restrict__ num,
    double* __restrict__ part, unsigned* __restrict__ cnt,
    float* __restrict__ out) {
    int r = (blockIdx.x << 8) + threadIdx.x;   // 32 blocks x 256 threads
    __shared__ double sd[256];
    sd[threadIdx.x] = (double)num[r] / (double)Z[r];
    __syncthreads();
    for (int st = 128; st > 0; st >>= 1) {
        if (threadIdx.x < st) sd[threadIdx.x] += sd[threadIdx.x + st];
        __syncthreads();
    }
    if (threadIdx.x == 0) {
        part[blockIdx.x] = sd[0];
        __threadfence();
        unsigned old = atomicAdd(cnt, 1u);
        if (old == 31u) {                // last block folds
            __threadfence();
            double a = 0.0;
            for (int k = 0; k < 32; ++k) a += part[k];
            out[0] = (float)(a / 67108864.0);   // / B^2
        }
    }
}

// ---------------- host launcher -----------------------------------------
extern "C" void kernel_launch(void* const* d_in, const int* in_sizes, int n_in,
                              void* d_out, int out_size, void* d_ws, size_t ws_size,
                              hipStream_t stream) {
    const float* V = (const float*)d_in[0];   // [8192, 512] f32
    const float* E = (const float*)d_in[1];   // [8192, 64]  f32
    float* out = (float*)d_out;
    char* ws = (char*)d_ws;

    float*         n_   = (float*)(ws + 0);            // 32 KB
    float*         ne   = (float*)(ws + 32768);        // 32 KB
    float*         Z    = (float*)(ws + 65536);        // 32 KB (init 1 in k_prep)
    float*         num  = (float*)(ws + 98304);        // 32 KB (init 0 in k_prep)
    unsigned char* VF8  = (unsigned char*)(ws + 131072);// 4 MB fp8 V frags
    _Float16*      EFh  = (_Float16*)(ws + 4325376);   // 1 MB
    double*        part = (double*)(ws + 5373952);     // 256 B
    unsigned*      cnt  = (unsigned*)(ws + 5374208);   // 4 B

    k_prep<<<512, 256, 0, stream>>>(V, E, n_, ne, Z, num, VF8, EFh, cnt);
    k_mega<<<2080, 256, 0, stream>>>(VF8, EFh, ne, n_, Z, num);
    k_red <<<32, 256, 0, stream>>>(Z, num, part, cnt, out);
}

// Round 15
// 119.976 us; speedup vs baseline: 1.0007x; 1.0007x over previous
//
#include <hip/hip_runtime.h>

// TangentSpaceLoss: loss = (1/B^2) sum_ij softmax_j(E E^T)_ij * ||v_i - v_j||^2
// B=8192, G=512, D=64.
//
// R28: R27 clean (k_mega 54.5, WRITE 4.06MB, conflicts 0, VGPR 84). Last
// surviving S-phase latency chain: the ballot body (fires ~always at im
// granularity) still does ~12-16 scalar LDS reads/im (sNeJ/sNJ per jn,
// sNeI/sNI per r) at ~120cyc each. R28 makes the body LDS-FREE:
//   nej = bj[jn]+SEL_T (exact: x-32+32 exact for x in [16,128], Sterbenz);
//   nnj -> hoisted bnj[4]; nei = ai4[r]+SEL_T; nni -> vector nni4/im.
// +8 regs (~90 V + 64 A = 154 < 168, 3 waves held). Else R27-exact,
// sched_barrier fences kept. Sentinel: WRITE 4.06MB.
// Predict: k_mega ->50-52, total ->115-118. If flat/spill: structural floor
// reached (G barrier-drain ~28 vs 17 MFMA floor + ~60us harness restores).
//   G: LDS-staged fp8 MFMA K=512 (m97): lane-linear VF8, 16x
//      global_load_lds(16B)/chunk, dbuf, 1 barrier/chunk, linear ds_read_b128.
//   S: fp16 MFMA (EFh frag-linear, B-frags hoisted), ballot-skip epilogue,
//      reg-hoisted predicates + LDS-free body, per-im batched ballot,
//      2-stage partial reduce, padded scr planes.
// Selection: s > min(ne_i,ne_j)-32 (safe superset). Softmax shift ne_i;
// diagonal w=1, wd=0 -> Z preinit 1.
//
// VF8: [rt 512][c 8][lane 64][16B]; lane l = q*16+m holds A-row m,
// K-quad q (bytes 0-7 = kc0, 8-15 = kc1).
// EFh: [rt 512][kc 2][m 16][k' 32] halfs.

#define SEL_T 32.0f

typedef _Float16 half8 __attribute__((ext_vector_type(8)));
typedef float    f32x4 __attribute__((ext_vector_type(4)));
typedef long     l2t   __attribute__((ext_vector_type(2)));

#define MFMA16(a, b, c) __builtin_amdgcn_mfma_f32_16x16x32_f16(a, b, c, 0, 0, 0)
#define MFMA8(a, b, c)  __builtin_amdgcn_mfma_f32_16x16x32_fp8_fp8(a, b, c, 0, 0, 0)

// Shared super-tile decode: blk0 -> (bx<=by), XCD-windowed.
__device__ __forceinline__ void st_decode(int blk0, int& bx, int& by) {
    int g = (blk0 & 7) * 260 + (blk0 >> 3);
    int SY = 0;
#pragma unroll
    for (int s = 1; s < 8; ++s) if (32 * s * s + 4 * s <= g) SY = s;
    int rr = g - (32 * SY * SY + 4 * SY);
    if (rr < 64 * SY) {                         // off-diagonal ST (full 8x8)
        int SX = rr >> 6, t = rr & 63;
        bx = (SX << 3) + (t & 7);
        by = (SY << 3) + (t >> 3);
    } else {                                    // diagonal ST (36 blocks)
        int t = rr - 64 * SY;
        int ly = 0;
#pragma unroll
        for (int s = 1; s < 8; ++s) if (s * (s + 1) / 2 <= t) ly = s;
        int lx = t - ly * (ly + 1) / 2;
        bx = (SY << 3) + lx;
        by = (SY << 3) + ly;
    }
}

// ---------------- K1: norms + fp8 V + fp16 E layouts + Z/num init -------
__global__ __launch_bounds__(256) void k_prep(
    const float* __restrict__ V, const float* __restrict__ E,
    float* __restrict__ n, float* __restrict__ ne,
    float* __restrict__ Z, float* __restrict__ num,
    unsigned char* __restrict__ VF8, _Float16* __restrict__ EFh,
    unsigned* __restrict__ cnt) {
    int rt = blockIdx.x;                       // 512 row-tiles of 16 rows
    int tid = threadIdx.x, wave = tid >> 6, lane = tid & 63;
    if (rt == 0 && tid == 0) *cnt = 0;
    int m = lane >> 2, q = lane & 3;
    int row = rt * 16 + m;
    const float* vr = V + (size_t)row * 512;
    float sn = 0.f;
#pragma unroll
    for (int it = 0; it < 2; ++it) {
        int c = wave + it * 4;                 // K-chunk of 64
        const float4* p0 = (const float4*)(vr + c * 64 + q * 8);
        const float4* p1 = (const float4*)(vr + c * 64 + 32 + q * 8);
        float4 a0 = p0[0], a1 = p0[1], b0 = p1[0], b1 = p1[1];
        int w0 = 0, w1 = 0, w2 = 0, w3 = 0;
        w0 = __builtin_amdgcn_cvt_pk_fp8_f32(a0.x, a0.y, w0, false);
        w0 = __builtin_amdgcn_cvt_pk_fp8_f32(a0.z, a0.w, w0, true);
        w1 = __builtin_amdgcn_cvt_pk_fp8_f32(a1.x, a1.y, w1, false);
        w1 = __builtin_amdgcn_cvt_pk_fp8_f32(a1.z, a1.w, w1, true);
        w2 = __builtin_amdgcn_cvt_pk_fp8_f32(b0.x, b0.y, w2, false);
        w2 = __builtin_amdgcn_cvt_pk_fp8_f32(b0.z, b0.w, w2, true);
        w3 = __builtin_amdgcn_cvt_pk_fp8_f32(b1.x, b1.y, w3, false);
        w3 = __builtin_amdgcn_cvt_pk_fp8_f32(b1.z, b1.w, w3, true);
        uint4 o;
        o.x = (unsigned)w0; o.y = (unsigned)w1;
        o.z = (unsigned)w2; o.w = (unsigned)w3;
        // LANE-LINEAR layout: frag for (m,q) -> reader-lane l = q*16+m,
        // byte offset l*16 = (q<<8) + (m<<4).
        *(uint4*)(VF8 + (((size_t)rt * 8 + c) << 10) + ((size_t)q << 8) + ((size_t)m << 4)) = o;
        sn += a0.x*a0.x + a0.y*a0.y + a0.z*a0.z + a0.w*a0.w
            + a1.x*a1.x + a1.y*a1.y + a1.z*a1.z + a1.w*a1.w
            + b0.x*b0.x + b0.y*b0.y + b0.z*b0.z + b0.w*b0.w
            + b1.x*b1.x + b1.y*b1.y + b1.z*b1.z + b1.w*b1.w;
    }
    __shared__ float sred[4][64];
    sred[wave][lane] = sn;
    __syncthreads();
    if (tid < 16) {
        float s = 0.f;
#pragma unroll
    for (int w = 0; w < 4; ++w)
#pragma unroll
            for (int qq = 0; qq < 4; ++qq) s += sred[w][tid * 4 + qq];
        int rr = rt * 16 + tid;
        n[rr] = s;
        Z[rr] = 1.0f;                          // diagonal w=1, wd=0
        num[rr] = 0.0f;
    }
    // E: threads 0..127: rl = t>>3, u = t&7, k in [u*8, u*8+8)
    if (tid < 128) {
        int rl = tid >> 3, u = tid & 7;
        int erow = rt * 16 + rl;
        const float4* er = (const float4*)(E + (size_t)erow * 64);
        float4 x0 = er[u * 2], x1 = er[u * 2 + 1];
        float xf[8] = {x0.x, x0.y, x0.z, x0.w, x1.x, x1.y, x1.z, x1.w};
        half8 h;
        float se = 0.f;
#pragma unroll
        for (int k = 0; k < 8; ++k) {
            h[k] = (_Float16)xf[k];
            se += xf[k] * xf[k];
        }
        int kc = u >> 2, qq = u & 3;
        *(half8*)(EFh + ((size_t)rt * 2 + kc) * 512 + rl * 32 + qq * 8) = h;
        se += __shfl_xor(se, 1, 64);
        se += __shfl_xor(se, 2, 64);
        se += __shfl_xor(se, 4, 64);
        if (u == 0) ne[erow] = se;
    }
}

// ---------------- K2: LDS-staged tile kernel (m97 structure) ------------
// 256 thr = 4 waves in 2x2 grid; wave tile 64x64 = 4x4 MFMA tiles.
// Per K-chunk: 16 async global_load_lds (4/wave) stage 16KB; dbuf; 1 barrier.
__global__ __launch_bounds__(256, 3) void k_mega(
    const unsigned char* __restrict__ VF8, const _Float16* __restrict__ EFh,
    const float* __restrict__ ne, const float* __restrict__ nrm,
    float* __restrict__ Z, float* __restrict__ num) {
    int bx, by;
    st_decode(blockIdx.x, bx, by);
    int i0 = bx << 7, j0 = by << 7;
    bool diag = (bx == by);

    __shared__ unsigned char ldsV[2][16384];   // [buf][slot 16][1KB]; 0-7 A, 8-15 B
    __shared__ float sNeI[128], sNeJ[128], sNI[128], sNJ[128];
    // scr: zi 8 planes x 132 (pad: worst 2-way = free), ni 8 x 132,
    //      zj 4 x 128, nj 4 x 128
    __shared__ float scr[2112 + 1024];

    int tid = threadIdx.x;
    if (tid < 128) { sNeI[tid] = ne[i0 + tid]; sNI[tid] = nrm[i0 + tid]; }
    else { sNeJ[tid - 128] = ne[j0 + tid - 128]; sNJ[tid - 128] = nrm[j0 + tid - 128]; }

    int wave = tid >> 6, lane = tid & 63;
    int m = lane & 15, quad = lane >> 4;
    int wi = wave & 1, wj = wave >> 1;
    int rtA0 = i0 >> 4, rtB0 = j0 >> 4;
    size_t loH = (size_t)(m * 32 + quad * 8);   // halfs (E frags)
    size_t lo16 = (size_t)lane << 4;            // lane-linear 16B frag offset

    __syncthreads();   // norms staged (also pre-loop barrier)

    // stage slot s (0-7: A rt rtA0+s; 8-15: B rt rtB0+s-8), chunk c -> buf
#define STAGE(buf, c)                                                           \
    {                                                                           \
        _Pragma("unroll")                                                       \
        for (int k = 0; k < 4; ++k) {                                           \
            int s = (wave << 2) + k;                                            \
            int rt = (s < 8) ? (rtA0 + s) : (rtB0 + s - 8);                     \
            __builtin_amdgcn_global_load_lds(                                   \
                (const unsigned int*)(VF8 + (((size_t)rt * 8 + (c)) << 10) + lo16), \
                (unsigned int*)(&ldsV[buf][(size_t)s << 10]), 16, 0, 0);        \
        }                                                                       \
    }

    // ---- G phase: K=512, 8 chunks; async-staged LDS, dbuf, 1 barrier/chunk
    f32x4 gacc[4][4] = {};
    STAGE(0, 0);
#pragma unroll
    for (int c = 0; c < 8; ++c) {
        __syncthreads();                       // buf[c&1] staged (vmcnt0+bar)
        if (c < 7) STAGE((c + 1) & 1, c + 1);  // async into other buf (race-free)
        l2t a[4], b[4];
#pragma unroll
        for (int im = 0; im < 4; ++im)
            a[im] = *(const l2t*)(&ldsV[c & 1][(size_t)((wi << 2) + im) << 10] + lo16);
#pragma unroll
        for (int jn = 0; jn < 4; ++jn)
            b[jn] = *(const l2t*)(&ldsV[c & 1][(size_t)(8 + (wj << 2) + jn) << 10] + lo16);
#pragma unroll
        for (int jn = 0; jn < 4; ++jn)
#pragma unroll
            for (int im = 0; im < 4; ++im) {
                gacc[im][jn] = MFMA8(a[im][0], b[jn][0], gacc[im][jn]);
                gacc[im][jn] = MFMA8(a[im][1], b[jn][1], gacc[im][jn]);
            }
    }
#undef STAGE

    // ---- fused S phase + epilogue (batched ballot, LDS-free body) ----
    int rtA = rtA0 + wi * 4;
    int rtB = rtB0 + wj * 4;
    half8 bh[4][2];
#pragma unroll
    for (int jn = 0; jn < 4; ++jn) {
        size_t bb = (size_t)(rtB + jn) * 2 * 512 + loH;
        bh[jn][0] = *(const half8*)(EFh + bb);
        bh[jn][1] = *(const half8*)(EFh + bb + 512);
    }
    // hoisted j-side inputs: bj[jn] = ne_j - SEL_T, bnj[jn] = ||v_j||^2
    float bj[4], bnj[4];
#pragma unroll
    for (int jn = 0; jn < 4; ++jn) {
        int jl = (wj << 6) + jn * 16 + m;
        bj[jn]  = sNeJ[jl] - SEL_T;
        bnj[jn] = sNJ[jl];
    }

    float zj[4] = {}, nj_[4] = {};
#pragma unroll
    for (int im = 0; im < 4; ++im) {
        size_t ab = (size_t)(rtA + im) * 2 * 512 + loH;
        half8 ah0 = *(const half8*)(EFh + ab);
        half8 ah1 = *(const half8*)(EFh + ab + 512);
        // vector reads: nei (pre-shifted) and nni for rows quad*4..+3
        int ibase = (wi << 6) + im * 16 + quad * 4;
        f32x4 ai4 = *(const f32x4*)(sNeI + ibase);
        ai4[0] -= SEL_T; ai4[1] -= SEL_T; ai4[2] -= SEL_T; ai4[3] -= SEL_T;
        f32x4 nni4 = *(const f32x4*)(sNI + ibase);
        f32x4 zi4 = {0.f, 0.f, 0.f, 0.f};
        f32x4 ni4 = {0.f, 0.f, 0.f, 0.f};
        // batch: all 4 jn ACC tiles back-to-back (8 pipelined MFMA16s)
        f32x4 accT[4];
#pragma unroll
        for (int jn = 0; jn < 4; ++jn) {
            f32x4 t = {0.f, 0.f, 0.f, 0.f};
            t = MFMA16(ah0, bh[jn][0], t);
            accT[jn] = MFMA16(ah1, bh[jn][1], t);
        }
        // 16 predicates -> ONE ballot; predicates NOT stored (recomputed
        // in the body: 2 ops each)
        bool anyp = false;
#pragma unroll
        for (int jn = 0; jn < 4; ++jn) {
            int jl = (wj << 6) + jn * 16 + m;
#pragma unroll
            for (int r = 0; r < 4; ++r) {
                bool pp = accT[jn][r] > fminf(ai4[r], bj[jn]);
                if (diag) pp = pp && ((i0 + ibase + r) < (j0 + jl));
                anyp |= pp;
            }
        }
        if (__builtin_amdgcn_ballot_w64(anyp)) {       // wave-uniform skip
#pragma unroll
            for (int jn = 0; jn < 4; ++jn) {
                int jl = (wj << 6) + jn * 16 + m;
                float nej = bj[jn] + SEL_T;            // register, exact
                float nnj = bnj[jn];
                f32x4 g4 = gacc[im][jn];
#pragma unroll
                for (int r = 0; r < 4; ++r) {
                    bool pp = accT[jn][r] > fminf(ai4[r], bj[jn]);
                    if (diag) pp = pp && ((i0 + ibase + r) < (j0 + jl));
                    if (pp) {
                        float nei = ai4[r] + SEL_T;    // register, exact
                        float nni = nni4[r];
                        float s = accT[jn][r];
                        float wiw = __expf(s - nei);
                        float wjw = __expf(s - nej);
                        float wd = nni + nnj - 2.f * g4[r];
                        zi4[r] += wiw;  ni4[r] += wiw * wd;
                        zj[jn] += wjw;  nj_[jn] += wjw * wd;
                    }
                }
            }
        }
        // i-side: 2-stage reduce (groups of 4 m-lanes), write 4 partials/row
#pragma unroll
        for (int msk = 1; msk < 4; msk <<= 1) {
#pragma unroll
            for (int r = 0; r < 4; ++r) {
                zi4[r] += __shfl_xor(zi4[r], msk, 64);
                ni4[r] += __shfl_xor(ni4[r], msk, 64);
            }
        }
        if ((m & 3) == 0) {
            int k = m >> 2;
            *(f32x4*)(scr + ((wj << 2) + k) * 132 + ibase)        = zi4;
            *(f32x4*)(scr + 1056 + ((wj << 2) + k) * 132 + ibase) = ni4;
        }
        __builtin_amdgcn_sched_barrier(0);     // fence cross-im hoisting
    }
    // j-side: 1-stage reduce (quad pairs), write 2 partials/col
#pragma unroll
    for (int jn = 0; jn < 4; ++jn) {
        zj[jn]  += __shfl_xor(zj[jn],  16, 64);
        nj_[jn] += __shfl_xor(nj_[jn], 16, 64);
    }
    if ((quad & 1) == 0) {
        int h = quad >> 1;
#pragma unroll
        for (int jn = 0; jn < 4; ++jn) {
            int jl = (wj << 6) + jn * 16 + m;
            scr[2112 + ((wi << 1) + h) * 128 + jl] = zj[jn];
            scr[2624 + ((wi << 1) + h) * 128 + jl] = nj_[jn];
        }
    }
    __syncthreads();
    // fold partial planes -> direct device atomics (zero-skip for empty rows)
    if (tid < 128) {
        float az = 0.f, an = 0.f;
#pragma unroll
        for (int p = 0; p < 8; ++p) {
            az += scr[p * 132 + tid];
            an += scr[1056 + p * 132 + tid];
        }
        if (az != 0.f || an != 0.f) {
            atomicAdd(Z + i0 + tid,   az);
            atomicAdd(num + i0 + tid, an);
        }
    } else {
        int cidx = tid - 128;
        float az = scr[2112 + cidx] + scr[2240 + cidx] + scr[2368 + cidx] + scr[2496 + cidx];
        float an = scr[2624 + cidx] + scr[2752 + cidx] + scr[2880 + cidx] + scr[3008 + cidx];
        if (az != 0.f || an != 0.f) {
            atomicAdd(Z + j0 + cidx,   az);
            atomicAdd(num + j0 + cidx, an);
        }
    }
}

// ------- K3: trivial 8192-row reduce + last-block final fold ------------
__global__ __launch_bounds__(256) void k_red(
    const float* __restrict__ Z, const float* __restrict__ num,
    double* __restrict__ part, unsigned* __restrict__ cnt,
    float* __restrict__ out) {
    int r = (blockIdx.x << 8) + threadIdx.x;   // 32 blocks x 256 threads
    __shared__ double sd[256];
    sd[threadIdx.x] = (double)num[r] / (double)Z[r];
    __syncthreads();
    for (int st = 128; st > 0; st >>= 1) {
        if (threadIdx.x < st) sd[threadIdx.x] += sd[threadIdx.x + st];
        __syncthreads();
    }
    if (threadIdx.x == 0) {
        part[blockIdx.x] = sd[0];
        __threadfence();
        unsigned old = atomicAdd(cnt, 1u);
        if (old == 31u) {                // last block folds
            __threadfence();
            double a = 0.0;
            for (int k = 0; k < 32; ++k) a += part[k];
            out[0] = (float)(a / 67108864.0);   // / B^2
        }
    }
}

// ---------------- host launcher -----------------------------------------
extern "C" void kernel_launch(void* const* d_in, const int* in_sizes, int n_in,
                              void* d_out, int out_size, void* d_ws, size_t ws_size,
                              hipStream_t stream) {
    const float* V = (const float*)d_in[0];   // [8192, 512] f32
    const float* E = (const float*)d_in[1];   // [8192, 64]  f32
    float* out = (float*)d_out;
    char* ws = (char*)d_ws;

    float*         n_   = (float*)(ws + 0);            // 32 KB
    float*         ne   = (float*)(ws + 32768);        // 32 KB
    float*         Z    = (float*)(ws + 65536);        // 32 KB (init 1 in k_prep)
    float*         num  = (float*)(ws + 98304);        // 32 KB (init 0 in k_prep)
    unsigned char* VF8  = (unsigned char*)(ws + 131072);// 4 MB fp8 V frags
    _Float16*      EFh  = (_Float16*)(ws + 4325376);   // 1 MB
    double*        part = (double*)(ws + 5373952);     // 256 B
    unsigned*      cnt  = (unsigned*)(ws + 5374208);   // 4 B

    k_prep<<<512, 256, 0, stream>>>(V, E, n_, ne, Z, num, VF8, EFh, cnt);
    k_mega<<<2080, 256, 0, stream>>>(VF8, EFh, ne, n_, Z, num);
    k_red <<<32, 256, 0, stream>>>(Z, num, part, cnt, out);
}